// Round 1
// baseline (546.386 us; speedup 1.0000x reference)
//
#include <hip/hip_runtime.h>

// Problem: HighQualityNSN2NLoss — B=16, H=W=768, all fp32, scalar fp32 out.
// x_ip1 (d_in[3]) is unused by the reference.
//
// Strategy: one full-bandwidth pass over {y_pred, x_i, W} computes every
// dense loss term + histograms for the quantiles + a compact list of
// flat&body pixels (~3000 of 9.4M). A second tiny pass evaluates the
// 19x19/7x7 Gaussian convs and the syn-loss only at those pixels, so the
// noise tensors (75 MB) are never fully read.

#define HH 768
#define WW 768
#define BB 16
#define HWSZ (HH * WW)
#define NPXD ((double)BB * (double)HWSZ)

#define NB 1024
#define NHIST (2 * NB)
#define TILE_X 64
#define TILE_Y 4
#define TILES_X (WW / TILE_X)          // 12
#define TILES_Y (HH / TILE_Y)          // 192
#define NTILES (TILES_X * TILES_Y * BB) // 36864

__device__ __forceinline__ float wredf(float v) {
#pragma unroll
  for (int o = 32; o > 0; o >>= 1) v += __shfl_down(v, o, 64);
  return v;
}
__device__ __forceinline__ unsigned wredu(unsigned v) {
#pragma unroll
  for (int o = 32; o > 0; o >>= 1) v += __shfl_down(v, o, 64);
  return v;
}

// accs: 0 rc, 1 sum_xi_body, 2 sum_yp_body, 3 edge_x, 4 edge_y,
//       5 tex, 6 hf, 7 ic, 8 lf, 9 mid, 10 syn
// cnts: 0 body, 1 tex, 2 flat, 3 fb (also fb_list append counter)

__global__ __launch_bounds__(256) void pass1_kernel(
    const float* __restrict__ yp, const float* __restrict__ xi,
    const float* __restrict__ wt, double* __restrict__ accs,
    unsigned* __restrict__ cnts, unsigned* __restrict__ fb_list, int fb_cap,
    unsigned* __restrict__ hist_parts) {
  __shared__ float s_yp[6][66];
  __shared__ float s_xi[6][66];
  __shared__ unsigned s_hist[NHIST];
  __shared__ float s_redf[4][8];
  __shared__ unsigned s_redc[4][3];

  const int tid = threadIdx.x;
  const int lane = tid & 63;
  const int wv = tid >> 6;
  const int tx = tid & 63;  // column within tile
  const int ty = tid >> 6;  // row within tile

  for (int i = tid; i < NHIST; i += 256) s_hist[i] = 0u;

  float a_rc = 0.f, a_sxi = 0.f, a_syp = 0.f, a_ex = 0.f, a_ey = 0.f;
  float a_tex = 0.f, a_hf = 0.f, a_ic = 0.f;
  unsigned c_body = 0u, c_tex = 0u, c_flat = 0u;

  for (int t = blockIdx.x; t < NTILES; t += gridDim.x) {
    const int tix = t % TILES_X;
    const int tiy = (t / TILES_X) % TILES_Y;
    const int b = t / (TILES_X * TILES_Y);
    const int x0 = tix * TILE_X;
    const int y0 = tiy * TILE_Y;
    const size_t base = (size_t)b * HWSZ;

    __syncthreads();  // protect LDS from previous iteration's readers
    for (int i = tid; i < 2 * 396; i += 256) {
      int j = i;
      const float* src = yp + base;
      float* dst = &s_yp[0][0];
      if (j >= 396) { j -= 396; src = xi + base; dst = &s_xi[0][0]; }
      const int r = j / 66, c = j - r * 66;
      const int gy = y0 - 1 + r, gx = x0 - 1 + c;
      float v = 0.f;
      if (gy >= 0 && gy < HH && gx >= 0 && gx < WW) v = src[gy * WW + gx];
      dst[r * 66 + c] = v;
    }
    __syncthreads();

    const int gx_ = x0 + tx, gy_ = y0 + ty;
    const float w = wt[base + (size_t)gy_ * WW + gx_];

    const float p00 = s_yp[ty][tx],     p01 = s_yp[ty][tx + 1],     p02 = s_yp[ty][tx + 2];
    const float p10 = s_yp[ty + 1][tx], p11 = s_yp[ty + 1][tx + 1], p12 = s_yp[ty + 1][tx + 2];
    const float p20 = s_yp[ty + 2][tx], p21 = s_yp[ty + 2][tx + 1], p22 = s_yp[ty + 2][tx + 2];
    const float i00 = s_xi[ty][tx],     i01 = s_xi[ty][tx + 1],     i02 = s_xi[ty][tx + 2];
    const float i10 = s_xi[ty + 1][tx], i11 = s_xi[ty + 1][tx + 1], i12 = s_xi[ty + 1][tx + 2];
    const float i20 = s_xi[ty + 2][tx], i21 = s_xi[ty + 2][tx + 1], i22 = s_xi[ty + 2][tx + 2];

    const float gxp = (p02 - p00) + 2.f * (p12 - p10) + (p22 - p20);
    const float gyp = (p20 - p00) + 2.f * (p21 - p01) + (p22 - p02);
    const float lapp = p01 + p10 + p12 + p21 - 4.f * p11;
    const float gxi_ = (i02 - i00) + 2.f * (i12 - i10) + (i22 - i20);
    const float gyi_ = (i20 - i00) + 2.f * (i21 - i01) + (i22 - i02);
    const float lapi = i01 + i10 + i12 + i21 - 4.f * i11;

    const float yv = p11, xv = i11;
    a_rc += fabsf(yv * w - xv * w);

    const bool body = (xv > 0.15f) && (xv < 0.85f);
    if (body) {
      c_body++;
      a_sxi += xv;
      a_syp += yv;
      int bx = (int)(xv * (float)NB);
      bx = bx < 0 ? 0 : (bx > NB - 1 ? NB - 1 : bx);
      int by = (int)(yv * (float)NB);
      by = by < 0 ? 0 : (by > NB - 1 ? NB - 1 : by);
      atomicAdd(&s_hist[bx], 1u);
      atomicAdd(&s_hist[NB + by], 1u);
    }

    a_ex += fabsf(gxp - gxi_);
    a_ey += fabsf(gyp - gyi_);

    const float gmi = sqrtf(gxi_ * gxi_ + gyi_ * gyi_ + 1e-8f);
    const float gmp = sqrtf(gxp * gxp + gyp * gyp + 1e-8f);

    if (gmi > 0.03f && gmi < 0.5f) {
      c_tex++;
      a_tex += fabsf(gmp - gmi);
    }
    if (gmi < 0.03f) {
      c_flat++;
      a_hf += fabsf(fabsf(lapp) - 0.3f * fabsf(lapi));
      a_ic += fmaxf(gmp - 2.0f * gmi, 0.f);
      if (body) {
        const unsigned idx = atomicAdd(&cnts[3], 1u);
        if ((int)idx < fb_cap)
          fb_list[idx] = (unsigned)(base + (size_t)gy_ * WW + gx_);
      }
    }
  }

  __syncthreads();
  for (int i = tid; i < NHIST; i += 256)
    hist_parts[(size_t)blockIdx.x * NHIST + i] = s_hist[i];

  float f0 = wredf(a_rc), f1 = wredf(a_sxi), f2 = wredf(a_syp);
  float f3 = wredf(a_ex), f4 = wredf(a_ey), f5 = wredf(a_tex);
  float f6 = wredf(a_hf), f7 = wredf(a_ic);
  unsigned u0 = wredu(c_body), u1 = wredu(c_tex), u2 = wredu(c_flat);
  if (lane == 0) {
    s_redf[wv][0] = f0; s_redf[wv][1] = f1; s_redf[wv][2] = f2; s_redf[wv][3] = f3;
    s_redf[wv][4] = f4; s_redf[wv][5] = f5; s_redf[wv][6] = f6; s_redf[wv][7] = f7;
    s_redc[wv][0] = u0; s_redc[wv][1] = u1; s_redc[wv][2] = u2;
  }
  __syncthreads();
  if (tid < 8) {
    double s = (double)s_redf[0][tid] + (double)s_redf[1][tid] +
               (double)s_redf[2][tid] + (double)s_redf[3][tid];
    atomicAdd(&accs[tid], s);
  } else if (tid < 11) {
    int k = tid - 8;
    unsigned s = s_redc[0][k] + s_redc[1][k] + s_redc[2][k] + s_redc[3][k];
    atomicAdd(&cnts[k], s);
  }
}

__global__ __launch_bounds__(256) void hist_reduce_kernel(
    const unsigned* __restrict__ hist_parts, unsigned* __restrict__ hist_final,
    int nparts) {
  unsigned acc[8];
#pragma unroll
  for (int k = 0; k < 8; k++) acc[k] = 0u;
  for (int p = blockIdx.x; p < nparts; p += gridDim.x) {
    const unsigned* row = hist_parts + (size_t)p * NHIST;
#pragma unroll
    for (int k = 0; k < 8; k++) acc[k] += row[threadIdx.x + k * 256];
  }
#pragma unroll
  for (int k = 0; k < 8; k++)
    if (acc[k]) atomicAdd(&hist_final[threadIdx.x + k * 256], acc[k]);
}

// One wave per flat&body pixel: G3 (19x19) on x_i/yp/x_mid, G1 (7x7) on
// x_i/yp, plus the syn term. Zero padding == skip out-of-bounds taps.
__global__ __launch_bounds__(256) void pass2_kernel(
    const float* __restrict__ yp, const float* __restrict__ xi,
    const float* __restrict__ xm, const float* __restrict__ npred,
    const float* __restrict__ nsyn, double* __restrict__ accs,
    const unsigned* __restrict__ cnts, const unsigned* __restrict__ fb_list,
    int fb_cap) {
  __shared__ float w3[19];
  __shared__ float w1[7];
  if (threadIdx.x == 0) {
    float tmp[19], s = 0.f;
    for (int i = 0; i < 19; i++) {
      float c = (float)(i - 9) / 3.0f;
      tmp[i] = expf(-0.5f * c * c);
      s += tmp[i];
    }
    for (int i = 0; i < 19; i++) w3[i] = tmp[i] / s;
    float tmp1[7], s1 = 0.f;
    for (int i = 0; i < 7; i++) {
      float c = (float)(i - 3);
      tmp1[i] = expf(-0.5f * c * c);
      s1 += tmp1[i];
    }
    for (int i = 0; i < 7; i++) w1[i] = tmp1[i] / s1;
  }
  __syncthreads();

  unsigned nfb = cnts[3];
  if (nfb > (unsigned)fb_cap) nfb = (unsigned)fb_cap;
  const int lane = threadIdx.x & 63;
  const int wid = (int)((blockIdx.x * blockDim.x + threadIdx.x) >> 6);
  const int nwaves = (int)((gridDim.x * blockDim.x) >> 6);

  for (int i = wid; i < (int)nfb; i += nwaves) {
    const unsigned px = fb_list[i];
    const int b = px / HWSZ;
    const int rem = px % HWSZ;
    const int y = rem / WW;
    const int x = rem % WW;
    const size_t base = (size_t)b * HWSZ;
    const float* xib = xi + base;
    const float* ypb = yp + base;
    const float* xmb = xm + base;

    float s_li = 0.f, s_lp = 0.f, s_lm = 0.f;
    for (int tap = lane; tap < 361; tap += 64) {
      const int r = tap / 19, c = tap - r * 19;
      const int gy = y + r - 9, gx = x + c - 9;
      if (gy >= 0 && gy < HH && gx >= 0 && gx < WW) {
        const float wgt = w3[r] * w3[c];
        const int o = gy * WW + gx;
        s_li += wgt * xib[o];
        s_lp += wgt * ypb[o];
        s_lm += wgt * xmb[o];
      }
    }
    float s_gi = 0.f, s_gp = 0.f;
    if (lane < 49) {
      const int r = lane / 7, c = lane - r * 7;
      const int gy = y + r - 3, gx = x + c - 3;
      if (gy >= 0 && gy < HH && gx >= 0 && gx < WW) {
        const float wgt = w1[r] * w1[c];
        const int o = gy * WW + gx;
        s_gi = wgt * xib[o];
        s_gp = wgt * ypb[o];
      }
    }
    s_li = wredf(s_li);
    s_lp = wredf(s_lp);
    s_lm = wredf(s_lm);
    s_gi = wredf(s_gi);
    s_gp = wredf(s_gp);
    if (lane == 0) {
      const float lf = fabsf((s_lp - s_lm) - 0.3f * (s_li - s_lm));
      const float mi_ = s_gi - s_li, mp_ = s_gp - s_lp;
      const float md = fabsf(fabsf(mp_) - 0.3f * fabsf(mi_));
      const float sy = fabsf(npred[px] - nsyn[px]);
      atomicAdd(&accs[8], (double)lf);
      atomicAdd(&accs[9], (double)md);
      atomicAdd(&accs[10], (double)sy);
    }
  }
}

__device__ double hquant(const unsigned* h, unsigned n, double q) {
  const double pos = q * (double)(n - 1u);
  double cum = 0.0;
  for (int b = 0; b < NB; b++) {
    const double m = (double)h[b];
    if (pos < cum + m) {
      const double local = pos - cum;
      return ((double)b + (local + 0.5) / m) * (1.0 / (double)NB);
    }
    cum += m;
  }
  return 1.0;
}

__global__ __launch_bounds__(256) void finalize_kernel(
    const double* __restrict__ accs, const unsigned* __restrict__ cnts,
    const unsigned* __restrict__ hist, float* __restrict__ out) {
  __shared__ unsigned sh[NHIST];
  for (int i = threadIdx.x; i < NHIST; i += 256) sh[i] = hist[i];
  __syncthreads();
  if (threadIdx.x != 0) return;

  const unsigned nb = cnts[0], ntex = cnts[1], nflat = cnts[2], nfb = cnts[3];
  const double loss_rc = accs[0] / NPXD;
  const double denb = (double)(nb > 0u ? nb : 1u);
  const double mean_in = accs[1] / denb;
  const double mean_pr = accs[2] / denb;

  double loss_hu = 0.0;
  if (nb > 4096u) {
    const double q25i = hquant(sh, nb, 0.25);
    const double q75i = hquant(sh, nb, 0.75);
    const double q25p = hquant(sh + NB, nb, 0.25);
    const double q75p = hquant(sh + NB, nb, 0.75);
    const double d = mean_pr - mean_in;
    loss_hu = d * d + 0.5 * ((q25p - q25i) * (q25p - q25i) +
                             (q75p - q75i) * (q75p - q75i));
  }

  const double loss_edge = accs[3] / NPXD + accs[4] / NPXD;
  const double loss_tex = (ntex > 100u) ? accs[5] / (double)(ntex ? ntex : 1u) : 0.0;
  const double loss_hf = (nflat > 100u) ? accs[6] / (double)(nflat ? nflat : 1u) : 0.0;
  const double loss_ic = (nflat > 100u) ? accs[7] / (double)(nflat ? nflat : 1u) : 0.0;
  const double denfb = (double)(nfb > 0u ? nfb : 1u);
  const double loss_lf = (nfb > 100u) ? accs[8] / denfb : 0.0;
  const double loss_mid = (nfb > 100u) ? accs[9] / denfb : 0.0;
  const double loss_syn = (nfb > 100u) ? accs[10] / denfb : 0.0;

  const double total = 2.0 * loss_rc + 1.5 * loss_hu + 1.0 * loss_edge +
                       0.8 * loss_tex + 1.5 * loss_hf + 0.8 * loss_mid +
                       0.6 * loss_lf + 1.0 * loss_syn + 0.8 * loss_ic;
  out[0] = (float)total;
}

extern "C" void kernel_launch(void* const* d_in, const int* in_sizes, int n_in,
                              void* d_out, int out_size, void* d_ws,
                              size_t ws_size, hipStream_t stream) {
  (void)in_sizes; (void)n_in; (void)out_size;
  const float* y_pred = (const float*)d_in[0];
  const float* noise_pred = (const float*)d_in[1];
  const float* x_i = (const float*)d_in[2];
  // d_in[3] = x_ip1: unused by the reference
  const float* x_mid = (const float*)d_in[4];
  const float* Wt = (const float*)d_in[5];
  const float* nsyn = (const float*)d_in[6];
  float* out = (float*)d_out;

  char* ws = (char*)d_ws;
  double* accs = (double*)ws;                       // 16 doubles
  unsigned* cnts = (unsigned*)(ws + 128);           // 16 uints
  unsigned* hist_final = (unsigned*)(ws + 256);     // 2048 uints
  const size_t FIXED = 16384;

  int fb_cap = 1 << 20;
  int nparts = 1024;
  size_t need = FIXED + (size_t)fb_cap * 4 + (size_t)nparts * NHIST * 4;
  if (need > ws_size) {
    fb_cap = 1 << 16;
    nparts = 256;
  }
  unsigned* fb_list = (unsigned*)(ws + FIXED);
  unsigned* hist_parts = (unsigned*)(ws + FIXED + (size_t)fb_cap * 4);

  hipMemsetAsync(ws, 0, FIXED, stream);
  pass1_kernel<<<nparts, 256, 0, stream>>>(y_pred, x_i, Wt, accs, cnts,
                                           fb_list, fb_cap, hist_parts);
  hist_reduce_kernel<<<64, 256, 0, stream>>>(hist_parts, hist_final, nparts);
  pass2_kernel<<<128, 256, 0, stream>>>(y_pred, x_i, x_mid, noise_pred, nsyn,
                                        accs, cnts, fb_list, fb_cap);
  finalize_kernel<<<1, 256, 0, stream>>>(accs, cnts, hist_final, out);
}

// Round 2
// 346.468 us; speedup vs baseline: 1.5770x; 1.5770x over previous
//
#include <hip/hip_runtime.h>

// HighQualityNSN2NLoss — B=16, H=W=768, fp32, scalar out. x_ip1 unused.
//
// pass1: register-rolling 3x3 stencil, one coalesced float4/lane/row per
//        tensor, shfl for x-neighbors. Computes rc/edge/tex/hf/ic, body
//        stats, 1024-bin histograms (quantiles), and the flat&body list.
// pass2: per-wave evaluation of G3(19x19)/G1(7x7) + syn only at fb pixels.
// finalize: parallel prefix-scan over the histograms + binary-search
//        quantiles (the old serial version was 160us of LDS latency).

#define HH 768
#define WW 768
#define BB 16
#define HWSZ (HH * WW)
#define NPXD ((double)BB * (double)HWSZ)

#define NB 1024
#define NHIST (2 * NB)

#define STRIPS 3          // 256-wide column strips
#define HSEG 16           // rows per wave-job
#define NSEG (HH / HSEG)  // 48
#define NJOBS (STRIPS * NSEG * BB)  // 2304
#define NBLK1 (NJOBS / 4)           // 576 blocks (4 waves each)

__device__ __forceinline__ float wredf(float v) {
#pragma unroll
  for (int o = 32; o > 0; o >>= 1) v += __shfl_down(v, o, 64);
  return v;
}
__device__ __forceinline__ unsigned wredu(unsigned v) {
#pragma unroll
  for (int o = 32; o > 0; o >>= 1) v += __shfl_down(v, o, 64);
  return v;
}

struct Row {
  float f[4];
  float l, r;  // left neighbor of f[0], right neighbor of f[3]
};

__device__ __forceinline__ Row load_row(const float* __restrict__ p, int y,
                                        int xl, int x0, int lane) {
  Row r;
  if (y < 0 || y >= HH) {
    r.f[0] = r.f[1] = r.f[2] = r.f[3] = 0.f;
    r.l = 0.f;
    r.r = 0.f;
    return r;
  }
  const float4 v = *(const float4*)(p + (size_t)y * WW + xl);
  r.f[0] = v.x; r.f[1] = v.y; r.f[2] = v.z; r.f[3] = v.w;
  float left = __shfl_up(v.w, 1, 64);
  float right = __shfl_down(v.x, 1, 64);
  if (lane == 0) left = (x0 > 0) ? p[(size_t)y * WW + x0 - 1] : 0.f;
  if (lane == 63) right = (x0 + 256 < WW) ? p[(size_t)y * WW + x0 + 256] : 0.f;
  r.l = left;
  r.r = right;
  return r;
}

#define LNB(row, j) ((j) == 0 ? (row).l : (row).f[(j)-1])
#define RNB(row, j) ((j) == 3 ? (row).r : (row).f[(j) + 1])

// accs: 0 rc, 1 sum_xi_body, 2 sum_yp_body, 3 edge_x, 4 edge_y,
//       5 tex, 6 hf, 7 ic, 8 lf, 9 mid, 10 syn
// cnts: 0 body, 1 tex, 2 flat, 3 fb (append counter)

__global__ __launch_bounds__(256) void pass1_kernel(
    const float* __restrict__ yp, const float* __restrict__ xi,
    const float* __restrict__ wt, double* __restrict__ accs,
    unsigned* __restrict__ cnts, unsigned* __restrict__ fb_list, int fb_cap,
    unsigned* __restrict__ hist_parts) {
  __shared__ unsigned s_hist[NHIST];
  __shared__ float s_redf[4][8];
  __shared__ unsigned s_redc[4][3];

  const int tid = threadIdx.x;
  const int lane = tid & 63;
  const int wv = tid >> 6;

  for (int i = tid; i < NHIST; i += 256) s_hist[i] = 0u;
  __syncthreads();

  const int job = blockIdx.x * 4 + wv;
  const int s = job % STRIPS;
  const int seg = (job / STRIPS) % NSEG;
  const int b = job / (STRIPS * NSEG);
  const int x0 = s * 256;
  const int y0 = seg * HSEG;
  const int xl = x0 + lane * 4;
  const size_t base = (size_t)b * HWSZ;
  const float* ypb = yp + base;
  const float* xib = xi + base;
  const float* wtb = wt + base;

  float a_rc = 0.f, a_sxi = 0.f, a_syp = 0.f, a_ex = 0.f, a_ey = 0.f;
  float a_tex = 0.f, a_hf = 0.f, a_ic = 0.f;
  unsigned c_body = 0u, c_tex = 0u, c_flat = 0u;

  Row pm1 = load_row(ypb, y0 - 1, xl, x0, lane);
  Row pc = load_row(ypb, y0, xl, x0, lane);
  Row im1 = load_row(xib, y0 - 1, xl, x0, lane);
  Row ic = load_row(xib, y0, xl, x0, lane);

  for (int y = y0; y < y0 + HSEG; y++) {
    const Row pp1 = load_row(ypb, y + 1, xl, x0, lane);
    const Row ip1 = load_row(xib, y + 1, xl, x0, lane);
    const float4 w4 = *(const float4*)(wtb + (size_t)y * WW + xl);
    const float wf[4] = {w4.x, w4.y, w4.z, w4.w};

#pragma unroll
    for (int j = 0; j < 4; j++) {
      const float p00 = LNB(pm1, j), p01 = pm1.f[j], p02 = RNB(pm1, j);
      const float p10 = LNB(pc, j),  p11 = pc.f[j],  p12 = RNB(pc, j);
      const float p20 = LNB(pp1, j), p21 = pp1.f[j], p22 = RNB(pp1, j);
      const float i00 = LNB(im1, j), i01 = im1.f[j], i02 = RNB(im1, j);
      const float i10 = LNB(ic, j),  i11 = ic.f[j],  i12 = RNB(ic, j);
      const float i20 = LNB(ip1, j), i21 = ip1.f[j], i22 = RNB(ip1, j);

      const float gxp = (p02 - p00) + 2.f * (p12 - p10) + (p22 - p20);
      const float gyp = (p20 - p00) + 2.f * (p21 - p01) + (p22 - p02);
      const float lapp = p01 + p10 + p12 + p21 - 4.f * p11;
      const float gxi_ = (i02 - i00) + 2.f * (i12 - i10) + (i22 - i20);
      const float gyi_ = (i20 - i00) + 2.f * (i21 - i01) + (i22 - i02);
      const float lapi = i01 + i10 + i12 + i21 - 4.f * i11;

      const float yv = p11, xv = i11;
      a_rc += fabsf(yv * wf[j] - xv * wf[j]);

      const bool body = (xv > 0.15f) && (xv < 0.85f);
      if (body) {
        c_body++;
        a_sxi += xv;
        a_syp += yv;
        int bx = (int)(xv * (float)NB);
        bx = bx < 0 ? 0 : (bx > NB - 1 ? NB - 1 : bx);
        int by = (int)(yv * (float)NB);
        by = by < 0 ? 0 : (by > NB - 1 ? NB - 1 : by);
        atomicAdd(&s_hist[bx], 1u);
        atomicAdd(&s_hist[NB + by], 1u);
      }

      a_ex += fabsf(gxp - gxi_);
      a_ey += fabsf(gyp - gyi_);

      const float gmi = sqrtf(gxi_ * gxi_ + gyi_ * gyi_ + 1e-8f);
      const float gmp = sqrtf(gxp * gxp + gyp * gyp + 1e-8f);

      if (gmi > 0.03f && gmi < 0.5f) {
        c_tex++;
        a_tex += fabsf(gmp - gmi);
      }
      if (gmi < 0.03f) {
        c_flat++;
        a_hf += fabsf(fabsf(lapp) - 0.3f * fabsf(lapi));
        a_ic += fmaxf(gmp - 2.0f * gmi, 0.f);
        if (body) {
          const unsigned idx = atomicAdd(&cnts[3], 1u);
          if ((int)idx < fb_cap)
            fb_list[idx] = (unsigned)(base + (size_t)y * WW + (xl + j));
        }
      }
    }
    pm1 = pc; pc = pp1;
    im1 = ic; ic = ip1;
  }

  __syncthreads();
  for (int i = tid; i < NHIST; i += 256)
    hist_parts[(size_t)blockIdx.x * NHIST + i] = s_hist[i];

  float f0 = wredf(a_rc), f1 = wredf(a_sxi), f2 = wredf(a_syp);
  float f3 = wredf(a_ex), f4 = wredf(a_ey), f5 = wredf(a_tex);
  float f6 = wredf(a_hf), f7 = wredf(a_ic);
  unsigned u0 = wredu(c_body), u1 = wredu(c_tex), u2 = wredu(c_flat);
  if (lane == 0) {
    s_redf[wv][0] = f0; s_redf[wv][1] = f1; s_redf[wv][2] = f2; s_redf[wv][3] = f3;
    s_redf[wv][4] = f4; s_redf[wv][5] = f5; s_redf[wv][6] = f6; s_redf[wv][7] = f7;
    s_redc[wv][0] = u0; s_redc[wv][1] = u1; s_redc[wv][2] = u2;
  }
  __syncthreads();
  if (tid < 8) {
    double sm = (double)s_redf[0][tid] + (double)s_redf[1][tid] +
                (double)s_redf[2][tid] + (double)s_redf[3][tid];
    atomicAdd(&accs[tid], sm);
  } else if (tid < 11) {
    int k = tid - 8;
    unsigned sm = s_redc[0][k] + s_redc[1][k] + s_redc[2][k] + s_redc[3][k];
    atomicAdd(&cnts[k], sm);
  }
}

__global__ __launch_bounds__(256) void hist_reduce_kernel(
    const unsigned* __restrict__ hist_parts, unsigned* __restrict__ hist_final,
    int nparts) {
  unsigned acc[8];
#pragma unroll
  for (int k = 0; k < 8; k++) acc[k] = 0u;
  for (int p = blockIdx.x; p < nparts; p += gridDim.x) {
    const unsigned* row = hist_parts + (size_t)p * NHIST;
#pragma unroll
    for (int k = 0; k < 8; k++) acc[k] += row[threadIdx.x + k * 256];
  }
#pragma unroll
  for (int k = 0; k < 8; k++)
    if (acc[k]) atomicAdd(&hist_final[threadIdx.x + k * 256], acc[k]);
}

__global__ __launch_bounds__(256) void pass2_kernel(
    const float* __restrict__ yp, const float* __restrict__ xi,
    const float* __restrict__ xm, const float* __restrict__ npred,
    const float* __restrict__ nsyn, double* __restrict__ accs,
    const unsigned* __restrict__ cnts, const unsigned* __restrict__ fb_list,
    int fb_cap) {
  __shared__ float w3[19];
  __shared__ float w1[7];
  if (threadIdx.x == 0) {
    float tmp[19], s = 0.f;
    for (int i = 0; i < 19; i++) {
      float c = (float)(i - 9) / 3.0f;
      tmp[i] = expf(-0.5f * c * c);
      s += tmp[i];
    }
    for (int i = 0; i < 19; i++) w3[i] = tmp[i] / s;
    float tmp1[7], s1 = 0.f;
    for (int i = 0; i < 7; i++) {
      float c = (float)(i - 3);
      tmp1[i] = expf(-0.5f * c * c);
      s1 += tmp1[i];
    }
    for (int i = 0; i < 7; i++) w1[i] = tmp1[i] / s1;
  }
  __syncthreads();

  unsigned nfb = cnts[3];
  if (nfb > (unsigned)fb_cap) nfb = (unsigned)fb_cap;
  const int lane = threadIdx.x & 63;
  const int wid = (int)((blockIdx.x * blockDim.x + threadIdx.x) >> 6);
  const int nwaves = (int)((gridDim.x * blockDim.x) >> 6);

  for (int i = wid; i < (int)nfb; i += nwaves) {
    const unsigned px = fb_list[i];
    const int b = px / HWSZ;
    const int rem = px % HWSZ;
    const int y = rem / WW;
    const int x = rem % WW;
    const size_t base = (size_t)b * HWSZ;
    const float* xib = xi + base;
    const float* ypb = yp + base;
    const float* xmb = xm + base;

    float s_li = 0.f, s_lp = 0.f, s_lm = 0.f;
    for (int tap = lane; tap < 361; tap += 64) {
      const int r = tap / 19, c = tap - r * 19;
      const int gy = y + r - 9, gx = x + c - 9;
      if (gy >= 0 && gy < HH && gx >= 0 && gx < WW) {
        const float wgt = w3[r] * w3[c];
        const int o = gy * WW + gx;
        s_li += wgt * xib[o];
        s_lp += wgt * ypb[o];
        s_lm += wgt * xmb[o];
      }
    }
    float s_gi = 0.f, s_gp = 0.f;
    if (lane < 49) {
      const int r = lane / 7, c = lane - r * 7;
      const int gy = y + r - 3, gx = x + c - 3;
      if (gy >= 0 && gy < HH && gx >= 0 && gx < WW) {
        const float wgt = w1[r] * w1[c];
        const int o = gy * WW + gx;
        s_gi = wgt * xib[o];
        s_gp = wgt * ypb[o];
      }
    }
    s_li = wredf(s_li);
    s_lp = wredf(s_lp);
    s_lm = wredf(s_lm);
    s_gi = wredf(s_gi);
    s_gp = wredf(s_gp);
    if (lane == 0) {
      const float lf = fabsf((s_lp - s_lm) - 0.3f * (s_li - s_lm));
      const float mi_ = s_gi - s_li, mp_ = s_gp - s_lp;
      const float md = fabsf(fabsf(mp_) - 0.3f * fabsf(mi_));
      const float sy = fabsf(npred[px] - nsyn[px]);
      atomicAdd(&accs[8], (double)lf);
      atomicAdd(&accs[9], (double)md);
      atomicAdd(&accs[10], (double)sy);
    }
  }
}

__global__ __launch_bounds__(256) void finalize_kernel(
    const double* __restrict__ accs, const unsigned* __restrict__ cnts,
    const unsigned* __restrict__ hist, float* __restrict__ out) {
  __shared__ unsigned sc[NHIST];   // inclusive cumsum (per half)
  __shared__ unsigned wsum[8];
  __shared__ double quant[4];
  const int tid = threadIdx.x;
  const int lane = tid & 63;
  const int wv = tid >> 6;

  if (tid < 4) quant[tid] = 0.0;

#pragma unroll
  for (int h = 0; h < 2; h++) {
    const int baseh = h * NB + tid * 4;
    const unsigned v0 = hist[baseh + 0];
    const unsigned v1 = hist[baseh + 1];
    const unsigned v2 = hist[baseh + 2];
    const unsigned v3 = hist[baseh + 3];
    const unsigned s = v0 + v1 + v2 + v3;
    unsigned scl = s;
#pragma unroll
    for (int o = 1; o < 64; o <<= 1) {
      const unsigned t = __shfl_up(scl, o, 64);
      if (lane >= o) scl += t;
    }
    if (lane == 63) wsum[h * 4 + wv] = scl;
    __syncthreads();
    unsigned woff = 0;
    for (int k = 0; k < wv; k++) woff += wsum[h * 4 + k];
    const unsigned excl = woff + scl - s;
    const unsigned c0 = excl + v0;
    const unsigned c1 = c0 + v1;
    const unsigned c2 = c1 + v2;
    const unsigned c3 = c2 + v3;
    sc[baseh + 0] = c0;
    sc[baseh + 1] = c1;
    sc[baseh + 2] = c2;
    sc[baseh + 3] = c3;
    __syncthreads();
  }

  const unsigned nb = cnts[0];
  if (tid < 4 && nb > 4096u) {
    const int h = tid >> 1;  // 0: x_i hist, 1: yp hist
    const double q = (tid & 1) ? 0.75 : 0.25;
    const double pos = q * (double)(nb - 1u);
    int lo = 0, hi = NB - 1;
    while (lo < hi) {
      const int mid = (lo + hi) >> 1;
      if ((double)sc[h * NB + mid] > pos) hi = mid; else lo = mid + 1;
    }
    const unsigned cum_before = (lo > 0) ? sc[h * NB + lo - 1] : 0u;
    const unsigned m = sc[h * NB + lo] - cum_before;
    const double local = pos - (double)cum_before;
    quant[tid] = ((double)lo + (local + 0.5) / (double)(m ? m : 1u)) *
                 (1.0 / (double)NB);
  }
  __syncthreads();
  if (tid != 0) return;

  const unsigned ntex = cnts[1], nflat = cnts[2], nfb = cnts[3];
  const double loss_rc = accs[0] / NPXD;
  const double denb = (double)(nb > 0u ? nb : 1u);
  const double mean_in = accs[1] / denb;
  const double mean_pr = accs[2] / denb;

  double loss_hu = 0.0;
  if (nb > 4096u) {
    const double q25i = quant[0], q75i = quant[1];
    const double q25p = quant[2], q75p = quant[3];
    const double d = mean_pr - mean_in;
    loss_hu = d * d + 0.5 * ((q25p - q25i) * (q25p - q25i) +
                             (q75p - q75i) * (q75p - q75i));
  }

  const double loss_edge = accs[3] / NPXD + accs[4] / NPXD;
  const double loss_tex = (ntex > 100u) ? accs[5] / (double)(ntex ? ntex : 1u) : 0.0;
  const double loss_hf = (nflat > 100u) ? accs[6] / (double)(nflat ? nflat : 1u) : 0.0;
  const double loss_ic = (nflat > 100u) ? accs[7] / (double)(nflat ? nflat : 1u) : 0.0;
  const double denfb = (double)(nfb > 0u ? nfb : 1u);
  const double loss_lf = (nfb > 100u) ? accs[8] / denfb : 0.0;
  const double loss_mid = (nfb > 100u) ? accs[9] / denfb : 0.0;
  const double loss_syn = (nfb > 100u) ? accs[10] / denfb : 0.0;

  const double total = 2.0 * loss_rc + 1.5 * loss_hu + 1.0 * loss_edge +
                       0.8 * loss_tex + 1.5 * loss_hf + 0.8 * loss_mid +
                       0.6 * loss_lf + 1.0 * loss_syn + 0.8 * loss_ic;
  out[0] = (float)total;
}

extern "C" void kernel_launch(void* const* d_in, const int* in_sizes, int n_in,
                              void* d_out, int out_size, void* d_ws,
                              size_t ws_size, hipStream_t stream) {
  (void)in_sizes; (void)n_in; (void)out_size;
  const float* y_pred = (const float*)d_in[0];
  const float* noise_pred = (const float*)d_in[1];
  const float* x_i = (const float*)d_in[2];
  // d_in[3] = x_ip1: unused by the reference
  const float* x_mid = (const float*)d_in[4];
  const float* Wt = (const float*)d_in[5];
  const float* nsyn = (const float*)d_in[6];
  float* out = (float*)d_out;

  char* ws = (char*)d_ws;
  double* accs = (double*)ws;                    // 16 doubles
  unsigned* cnts = (unsigned*)(ws + 128);        // 16 uints
  unsigned* hist_final = (unsigned*)(ws + 256);  // 2048 uints
  const size_t FIXED = 16384;

  int fb_cap = 1 << 20;
  size_t need = FIXED + (size_t)fb_cap * 4 + (size_t)NBLK1 * NHIST * 4;
  if (need > ws_size) fb_cap = 1 << 16;
  unsigned* fb_list = (unsigned*)(ws + FIXED);
  unsigned* hist_parts = (unsigned*)(ws + FIXED + (size_t)fb_cap * 4);

  hipMemsetAsync(ws, 0, FIXED, stream);
  pass1_kernel<<<NBLK1, 256, 0, stream>>>(y_pred, x_i, Wt, accs, cnts,
                                          fb_list, fb_cap, hist_parts);
  hist_reduce_kernel<<<64, 256, 0, stream>>>(hist_parts, hist_final, NBLK1);
  pass2_kernel<<<256, 256, 0, stream>>>(y_pred, x_i, x_mid, noise_pred, nsyn,
                                        accs, cnts, fb_list, fb_cap);
  finalize_kernel<<<1, 256, 0, stream>>>(accs, cnts, hist_final, out);
}

// Round 3
// 262.147 us; speedup vs baseline: 2.0843x; 1.3217x over previous
//
#include <hip/hip_runtime.h>

// HighQualityNSN2NLoss — B=16, H=W=768, fp32, scalar out. x_ip1 unused.
//
// R3 changes (atomics were the bottleneck, not bandwidth):
//  - pass1: per-wave LDS buffering of the flat&body list -> 1 global atomic
//    per wave (was 1 per fb pixel, ~10.5k serialized same-address atomics).
//    Block hist flushed straight into the global histogram (hist_reduce
//    kernel removed). 768 blocks = exactly 3/CU.
//  - pass2: lf/mid/syn accumulated in registers, 3 global atomics per BLOCK
//    (was 3 per pixel = 31.5k serialized fp64 atomics = the whole 104us).
//    19x19 tap loop unrolled with interior fast path -> 18 loads in flight.

#define HH 768
#define WW 768
#define BB 16
#define HWSZ (HH * WW)
#define NPXD ((double)BB * (double)HWSZ)

#define NB 1024
#define NHIST (2 * NB)

#define STRIPS 3           // 256-wide column strips
#define HSEG 12            // rows per wave-job
#define NSEG (HH / HSEG)   // 64
#define NJOBS (STRIPS * NSEG * BB)  // 3072
#define NBLK1 (NJOBS / 4)           // 768 blocks (4 waves each) = 3/CU

#define FBBUF 128          // per-wave fb buffer (expected ~3.4 hits/wave)

__device__ __forceinline__ float wredf(float v) {
#pragma unroll
  for (int o = 32; o > 0; o >>= 1) v += __shfl_down(v, o, 64);
  return v;
}
__device__ __forceinline__ unsigned wredu(unsigned v) {
#pragma unroll
  for (int o = 32; o > 0; o >>= 1) v += __shfl_down(v, o, 64);
  return v;
}

struct Row {
  float f[4];
  float l, r;
};

__device__ __forceinline__ Row load_row(const float* __restrict__ p, int y,
                                        int xl, int x0, int lane) {
  Row r;
  if (y < 0 || y >= HH) {
    r.f[0] = r.f[1] = r.f[2] = r.f[3] = 0.f;
    r.l = 0.f;
    r.r = 0.f;
    return r;
  }
  const float4 v = *(const float4*)(p + (size_t)y * WW + xl);
  r.f[0] = v.x; r.f[1] = v.y; r.f[2] = v.z; r.f[3] = v.w;
  float left = __shfl_up(v.w, 1, 64);
  float right = __shfl_down(v.x, 1, 64);
  if (lane == 0) left = (x0 > 0) ? p[(size_t)y * WW + x0 - 1] : 0.f;
  if (lane == 63) right = (x0 + 256 < WW) ? p[(size_t)y * WW + x0 + 256] : 0.f;
  r.l = left;
  r.r = right;
  return r;
}

#define LNB(row, j) ((j) == 0 ? (row).l : (row).f[(j)-1])
#define RNB(row, j) ((j) == 3 ? (row).r : (row).f[(j) + 1])

// accs: 0 rc, 1 sum_xi_body, 2 sum_yp_body, 3 edge_x, 4 edge_y,
//       5 tex, 6 hf, 7 ic, 8 lf, 9 mid, 10 syn
// cnts: 0 body, 1 tex, 2 flat, 3 fb (append counter)

__global__ __launch_bounds__(256) void pass1_kernel(
    const float* __restrict__ yp, const float* __restrict__ xi,
    const float* __restrict__ wt, double* __restrict__ accs,
    unsigned* __restrict__ cnts, unsigned* __restrict__ fb_list, int fb_cap,
    unsigned* __restrict__ hist_final) {
  __shared__ unsigned s_hist[NHIST];
  __shared__ unsigned s_fb[4][FBBUF];
  __shared__ unsigned s_fbn[4];
  __shared__ float s_redf[4][8];
  __shared__ unsigned s_redc[4][3];

  const int tid = threadIdx.x;
  const int lane = tid & 63;
  const int wv = tid >> 6;
  const unsigned long long lmask_lt = (1ull << lane) - 1ull;

  for (int i = tid; i < NHIST; i += 256) s_hist[i] = 0u;
  if (lane == 0) s_fbn[wv] = 0u;
  __syncthreads();

  const int job = blockIdx.x * 4 + wv;
  const int s = job % STRIPS;
  const int seg = (job / STRIPS) % NSEG;
  const int b = job / (STRIPS * NSEG);
  const int x0 = s * 256;
  const int y0 = seg * HSEG;
  const int xl = x0 + lane * 4;
  const size_t base = (size_t)b * HWSZ;
  const float* ypb = yp + base;
  const float* xib = xi + base;
  const float* wtb = wt + base;

  float a_rc = 0.f, a_sxi = 0.f, a_syp = 0.f, a_ex = 0.f, a_ey = 0.f;
  float a_tex = 0.f, a_hf = 0.f, a_ic = 0.f;
  unsigned c_body = 0u, c_tex = 0u, c_flat = 0u;

  Row pm1 = load_row(ypb, y0 - 1, xl, x0, lane);
  Row pc = load_row(ypb, y0, xl, x0, lane);
  Row im1 = load_row(xib, y0 - 1, xl, x0, lane);
  Row icr = load_row(xib, y0, xl, x0, lane);

  for (int y = y0; y < y0 + HSEG; y++) {
    const Row pp1 = load_row(ypb, y + 1, xl, x0, lane);
    const Row ip1 = load_row(xib, y + 1, xl, x0, lane);
    const float4 w4 = *(const float4*)(wtb + (size_t)y * WW + xl);
    const float wf[4] = {w4.x, w4.y, w4.z, w4.w};

#pragma unroll
    for (int j = 0; j < 4; j++) {
      const float p00 = LNB(pm1, j), p01 = pm1.f[j], p02 = RNB(pm1, j);
      const float p10 = LNB(pc, j),  p11 = pc.f[j],  p12 = RNB(pc, j);
      const float p20 = LNB(pp1, j), p21 = pp1.f[j], p22 = RNB(pp1, j);
      const float i00 = LNB(im1, j), i01 = im1.f[j], i02 = RNB(im1, j);
      const float i10 = LNB(icr, j), i11 = icr.f[j], i12 = RNB(icr, j);
      const float i20 = LNB(ip1, j), i21 = ip1.f[j], i22 = RNB(ip1, j);

      const float gxp = (p02 - p00) + 2.f * (p12 - p10) + (p22 - p20);
      const float gyp = (p20 - p00) + 2.f * (p21 - p01) + (p22 - p02);
      const float lapp = p01 + p10 + p12 + p21 - 4.f * p11;
      const float gxi_ = (i02 - i00) + 2.f * (i12 - i10) + (i22 - i20);
      const float gyi_ = (i20 - i00) + 2.f * (i21 - i01) + (i22 - i02);
      const float lapi = i01 + i10 + i12 + i21 - 4.f * i11;

      const float yv = p11, xv = i11;
      a_rc += fabsf(yv * wf[j] - xv * wf[j]);

      const bool body = (xv > 0.15f) && (xv < 0.85f);
      if (body) {
        c_body++;
        a_sxi += xv;
        a_syp += yv;
        int bx = (int)(xv * (float)NB);
        bx = bx < 0 ? 0 : (bx > NB - 1 ? NB - 1 : bx);
        int by = (int)(yv * (float)NB);
        by = by < 0 ? 0 : (by > NB - 1 ? NB - 1 : by);
        atomicAdd(&s_hist[bx], 1u);
        atomicAdd(&s_hist[NB + by], 1u);
      }

      a_ex += fabsf(gxp - gxi_);
      a_ey += fabsf(gyp - gyi_);

      const float gmi = sqrtf(gxi_ * gxi_ + gyi_ * gyi_ + 1e-8f);
      const float gmp = sqrtf(gxp * gxp + gyp * gyp + 1e-8f);

      if (gmi > 0.03f && gmi < 0.5f) {
        c_tex++;
        a_tex += fabsf(gmp - gmi);
      }
      const bool flat = gmi < 0.03f;
      if (flat) {
        c_flat++;
        a_hf += fabsf(fabsf(lapp) - 0.3f * fabsf(lapi));
        a_ic += fmaxf(gmp - 2.0f * gmi, 0.f);
      }
      // wave-aggregated append of flat&body pixels
      const bool qual = flat && body;
      const unsigned long long m = __ballot(qual);
      if (m) {
        const unsigned bofs = s_fbn[wv];
        if (qual) {
          const unsigned p = bofs + (unsigned)__popcll(m & lmask_lt);
          const unsigned gidx = (unsigned)(base + (size_t)y * WW + (xl + j));
          if (p < FBBUF) {
            s_fb[wv][p] = gidx;
          } else {  // overflow fallback (never hit on bench data)
            const unsigned gi = atomicAdd(&cnts[3], 1u);
            if ((int)gi < fb_cap) fb_list[gi] = gidx;
          }
        }
        s_fbn[wv] = bofs + (unsigned)__popcll(m);  // all lanes, same value
      }
    }
    pm1 = pc; pc = pp1;
    im1 = icr; icr = ip1;
  }

  // flush per-wave fb buffer: ONE global atomic per wave
  {
    unsigned n = s_fbn[wv];
    if (n > FBBUF) n = FBBUF;
    unsigned gbase = 0u;
    if (lane == 0 && n > 0) gbase = atomicAdd(&cnts[3], n);
    gbase = __shfl(gbase, 0, 64);
    for (unsigned i = lane; i < n; i += 64) {
      const unsigned gi = gbase + i;
      if ((int)gi < fb_cap) fb_list[gi] = s_fb[wv][i];
    }
  }

  __syncthreads();
  // flush block histogram straight into the global one (bins spread across
  // channels; ~768 adds per bin total, overlapped with other blocks' work)
  for (int i = tid; i < NHIST; i += 256) {
    const unsigned v = s_hist[i];
    if (v) atomicAdd(&hist_final[i], v);
  }

  float f0 = wredf(a_rc), f1 = wredf(a_sxi), f2 = wredf(a_syp);
  float f3 = wredf(a_ex), f4 = wredf(a_ey), f5 = wredf(a_tex);
  float f6 = wredf(a_hf), f7 = wredf(a_ic);
  unsigned u0 = wredu(c_body), u1 = wredu(c_tex), u2 = wredu(c_flat);
  if (lane == 0) {
    s_redf[wv][0] = f0; s_redf[wv][1] = f1; s_redf[wv][2] = f2; s_redf[wv][3] = f3;
    s_redf[wv][4] = f4; s_redf[wv][5] = f5; s_redf[wv][6] = f6; s_redf[wv][7] = f7;
    s_redc[wv][0] = u0; s_redc[wv][1] = u1; s_redc[wv][2] = u2;
  }
  __syncthreads();
  if (tid < 8) {
    double sm = (double)s_redf[0][tid] + (double)s_redf[1][tid] +
                (double)s_redf[2][tid] + (double)s_redf[3][tid];
    atomicAdd(&accs[tid], sm);
  } else if (tid < 11) {
    int k = tid - 8;
    unsigned sm = s_redc[0][k] + s_redc[1][k] + s_redc[2][k] + s_redc[3][k];
    atomicAdd(&cnts[k], sm);
  }
}

__global__ __launch_bounds__(256) void pass2_kernel(
    const float* __restrict__ yp, const float* __restrict__ xi,
    const float* __restrict__ xm, const float* __restrict__ npred,
    const float* __restrict__ nsyn, double* __restrict__ accs,
    const unsigned* __restrict__ cnts, const unsigned* __restrict__ fb_list,
    int fb_cap) {
  __shared__ float w3[19];
  __shared__ float w1[7];
  __shared__ double s_red[4][3];
  const int tid = threadIdx.x;
  const int lane = tid & 63;
  const int wv = tid >> 6;

  if (tid == 0) {
    float tmp[19], s = 0.f;
    for (int i = 0; i < 19; i++) {
      float c = (float)(i - 9) / 3.0f;
      tmp[i] = expf(-0.5f * c * c);
      s += tmp[i];
    }
    for (int i = 0; i < 19; i++) w3[i] = tmp[i] / s;
    float tmp1[7], s1 = 0.f;
    for (int i = 0; i < 7; i++) {
      float c = (float)(i - 3);
      tmp1[i] = expf(-0.5f * c * c);
      s1 += tmp1[i];
    }
    for (int i = 0; i < 7; i++) w1[i] = tmp1[i] / s1;
  }
  __syncthreads();

  unsigned nfb = cnts[3];
  if (nfb > (unsigned)fb_cap) nfb = (unsigned)fb_cap;
  const int wid = (int)((blockIdx.x * blockDim.x + tid) >> 6);
  const int nwaves = (int)((gridDim.x * blockDim.x) >> 6);

  double w_lf = 0.0, w_md = 0.0, w_sy = 0.0;  // lane-0 accumulators

  for (int i = wid; i < (int)nfb; i += nwaves) {
    const unsigned px = fb_list[i];
    const int b = (int)(px / (unsigned)HWSZ);
    const int rem = (int)(px % (unsigned)HWSZ);
    const int y = rem / WW;
    const int x = rem % WW;
    const size_t base = (size_t)b * HWSZ;
    const float* xib = xi + base;
    const float* ypb = yp + base;
    const float* xmb = xm + base;

    float npv = 0.f, nsv = 0.f;
    if (lane == 0) { npv = npred[px]; nsv = nsyn[px]; }

    float s_li = 0.f, s_lp = 0.f, s_lm = 0.f;
    float s_gi = 0.f, s_gp = 0.f;
    const bool interior = (y >= 9) && (y < HH - 9) && (x >= 9) && (x < WW - 9);
    if (interior) {
#pragma unroll
      for (int k = 0; k < 6; k++) {
        const int tap = lane + 64 * k;
        if (tap < 361) {
          const int r = tap / 19, c = tap - r * 19;
          const float wgt = w3[r] * w3[c];
          const int o = (y + r - 9) * WW + (x + c - 9);
          s_li += wgt * xib[o];
          s_lp += wgt * ypb[o];
          s_lm += wgt * xmb[o];
        }
      }
      if (lane < 49) {
        const int r = lane / 7, c = lane - r * 7;
        const float wgt = w1[r] * w1[c];
        const int o = (y + r - 3) * WW + (x + c - 3);
        s_gi = wgt * xib[o];
        s_gp = wgt * ypb[o];
      }
    } else {
#pragma unroll
      for (int k = 0; k < 6; k++) {
        const int tap = lane + 64 * k;
        if (tap < 361) {
          const int r = tap / 19, c = tap - r * 19;
          const int gy = y + r - 9, gx = x + c - 9;
          if (gy >= 0 && gy < HH && gx >= 0 && gx < WW) {
            const float wgt = w3[r] * w3[c];
            const int o = gy * WW + gx;
            s_li += wgt * xib[o];
            s_lp += wgt * ypb[o];
            s_lm += wgt * xmb[o];
          }
        }
      }
      if (lane < 49) {
        const int r = lane / 7, c = lane - r * 7;
        const int gy = y + r - 3, gx = x + c - 3;
        if (gy >= 0 && gy < HH && gx >= 0 && gx < WW) {
          const float wgt = w1[r] * w1[c];
          const int o = gy * WW + gx;
          s_gi = wgt * xib[o];
          s_gp = wgt * ypb[o];
        }
      }
    }
    s_li = wredf(s_li);
    s_lp = wredf(s_lp);
    s_lm = wredf(s_lm);
    s_gi = wredf(s_gi);
    s_gp = wredf(s_gp);
    if (lane == 0) {
      const float lf = fabsf((s_lp - s_lm) - 0.3f * (s_li - s_lm));
      const float mi_ = s_gi - s_li, mp_ = s_gp - s_lp;
      const float md = fabsf(fabsf(mp_) - 0.3f * fabsf(mi_));
      w_lf += (double)lf;
      w_md += (double)md;
      w_sy += (double)fabsf(npv - nsv);
    }
  }

  if (lane == 0) {
    s_red[wv][0] = w_lf; s_red[wv][1] = w_md; s_red[wv][2] = w_sy;
  }
  __syncthreads();
  if (tid < 3) {
    const double t = s_red[0][tid] + s_red[1][tid] + s_red[2][tid] + s_red[3][tid];
    if (t != 0.0) atomicAdd(&accs[8 + tid], t);
  }
}

__global__ __launch_bounds__(256) void finalize_kernel(
    const double* __restrict__ accs, const unsigned* __restrict__ cnts,
    const unsigned* __restrict__ hist, float* __restrict__ out) {
  __shared__ unsigned sc[NHIST];
  __shared__ unsigned wsum[8];
  __shared__ double quant[4];
  const int tid = threadIdx.x;
  const int lane = tid & 63;
  const int wv = tid >> 6;

  if (tid < 4) quant[tid] = 0.0;

#pragma unroll
  for (int h = 0; h < 2; h++) {
    const int baseh = h * NB + tid * 4;
    const unsigned v0 = hist[baseh + 0];
    const unsigned v1 = hist[baseh + 1];
    const unsigned v2 = hist[baseh + 2];
    const unsigned v3 = hist[baseh + 3];
    const unsigned s = v0 + v1 + v2 + v3;
    unsigned scl = s;
#pragma unroll
    for (int o = 1; o < 64; o <<= 1) {
      const unsigned t = __shfl_up(scl, o, 64);
      if (lane >= o) scl += t;
    }
    if (lane == 63) wsum[h * 4 + wv] = scl;
    __syncthreads();
    unsigned woff = 0;
    for (int k = 0; k < wv; k++) woff += wsum[h * 4 + k];
    const unsigned excl = woff + scl - s;
    const unsigned c0 = excl + v0;
    const unsigned c1 = c0 + v1;
    const unsigned c2 = c1 + v2;
    const unsigned c3 = c2 + v3;
    sc[baseh + 0] = c0;
    sc[baseh + 1] = c1;
    sc[baseh + 2] = c2;
    sc[baseh + 3] = c3;
    __syncthreads();
  }

  const unsigned nb = cnts[0];
  if (tid < 4 && nb > 4096u) {
    const int h = tid >> 1;
    const double q = (tid & 1) ? 0.75 : 0.25;
    const double pos = q * (double)(nb - 1u);
    int lo = 0, hi = NB - 1;
    while (lo < hi) {
      const int mid = (lo + hi) >> 1;
      if ((double)sc[h * NB + mid] > pos) hi = mid; else lo = mid + 1;
    }
    const unsigned cum_before = (lo > 0) ? sc[h * NB + lo - 1] : 0u;
    const unsigned m = sc[h * NB + lo] - cum_before;
    const double local = pos - (double)cum_before;
    quant[tid] = ((double)lo + (local + 0.5) / (double)(m ? m : 1u)) *
                 (1.0 / (double)NB);
  }
  __syncthreads();
  if (tid != 0) return;

  const unsigned ntex = cnts[1], nflat = cnts[2], nfb = cnts[3];
  const double loss_rc = accs[0] / NPXD;
  const double denb = (double)(nb > 0u ? nb : 1u);
  const double mean_in = accs[1] / denb;
  const double mean_pr = accs[2] / denb;

  double loss_hu = 0.0;
  if (nb > 4096u) {
    const double q25i = quant[0], q75i = quant[1];
    const double q25p = quant[2], q75p = quant[3];
    const double d = mean_pr - mean_in;
    loss_hu = d * d + 0.5 * ((q25p - q25i) * (q25p - q25i) +
                             (q75p - q75i) * (q75p - q75i));
  }

  const double loss_edge = accs[3] / NPXD + accs[4] / NPXD;
  const double loss_tex = (ntex > 100u) ? accs[5] / (double)(ntex ? ntex : 1u) : 0.0;
  const double loss_hf = (nflat > 100u) ? accs[6] / (double)(nflat ? nflat : 1u) : 0.0;
  const double loss_ic = (nflat > 100u) ? accs[7] / (double)(nflat ? nflat : 1u) : 0.0;
  const double denfb = (double)(nfb > 0u ? nfb : 1u);
  const double loss_lf = (nfb > 100u) ? accs[8] / denfb : 0.0;
  const double loss_mid = (nfb > 100u) ? accs[9] / denfb : 0.0;
  const double loss_syn = (nfb > 100u) ? accs[10] / denfb : 0.0;

  const double total = 2.0 * loss_rc + 1.5 * loss_hu + 1.0 * loss_edge +
                       0.8 * loss_tex + 1.5 * loss_hf + 0.8 * loss_mid +
                       0.6 * loss_lf + 1.0 * loss_syn + 0.8 * loss_ic;
  out[0] = (float)total;
}

extern "C" void kernel_launch(void* const* d_in, const int* in_sizes, int n_in,
                              void* d_out, int out_size, void* d_ws,
                              size_t ws_size, hipStream_t stream) {
  (void)in_sizes; (void)n_in; (void)out_size;
  const float* y_pred = (const float*)d_in[0];
  const float* noise_pred = (const float*)d_in[1];
  const float* x_i = (const float*)d_in[2];
  // d_in[3] = x_ip1: unused by the reference
  const float* x_mid = (const float*)d_in[4];
  const float* Wt = (const float*)d_in[5];
  const float* nsyn = (const float*)d_in[6];
  float* out = (float*)d_out;

  char* ws = (char*)d_ws;
  double* accs = (double*)ws;                    // 16 doubles
  unsigned* cnts = (unsigned*)(ws + 128);        // 16 uints
  unsigned* hist_final = (unsigned*)(ws + 256);  // 2048 uints
  const size_t FIXED = 16384;

  size_t avail = (ws_size > FIXED) ? (ws_size - FIXED) : 0;
  long long cap = (long long)(avail / 4);
  if (cap > (long long)BB * HWSZ) cap = (long long)BB * HWSZ;
  int fb_cap = (int)cap;
  unsigned* fb_list = (unsigned*)(ws + FIXED);

  hipMemsetAsync(ws, 0, FIXED, stream);
  pass1_kernel<<<NBLK1, 256, 0, stream>>>(y_pred, x_i, Wt, accs, cnts,
                                          fb_list, fb_cap, hist_final);
  pass2_kernel<<<256, 256, 0, stream>>>(y_pred, x_i, x_mid, noise_pred, nsyn,
                                        accs, cnts, fb_list, fb_cap);
  finalize_kernel<<<1, 256, 0, stream>>>(accs, cnts, hist_final, out);
}